// Round 5
// baseline (375.650 us; speedup 1.0000x reference)
//
#include <hip/hip_runtime.h>

// Residual GCN, MI355X. B=8, N=2048, D=128. External dtype fp32 (verified R3).
// out = dinv_i * (A @ (dinv_j * leakyrelu(X@W + b))) [+ X]
// Internal bf16 + MFMA 16x16x32 bf16, fp32 accumulate.
// R5: big GEMM K-split 2 (grid 512 = 2 blocks/CU) + k_fin combine kernels.

typedef short bf16x8 __attribute__((ext_vector_type(8)));
typedef float f32x4 __attribute__((ext_vector_type(4)));

#define PLANE 2097152  // 16384*128

static __device__ __forceinline__ float bf2f(unsigned short h) {
    union { unsigned int u; float f; } v; v.u = ((unsigned int)h) << 16; return v.f;
}
static __device__ __forceinline__ unsigned short f2bf(float x) {  // RNE
    union { float f; unsigned int u; } v; v.f = x;
    return (unsigned short)((v.u + 0x7FFFu + ((v.u >> 16) & 1u)) >> 16);
}

// ---- fused: adj rowsum -> dinv, adj fp32 -> bf16, W transpose, bias ------
__global__ __launch_bounds__(256) void k_pre(const float* __restrict__ adj,
                                             const float* __restrict__ W1,
                                             const float* __restrict__ W2,
                                             const float* __restrict__ W3,
                                             const float* __restrict__ b1,
                                             const float* __restrict__ b2,
                                             const float* __restrict__ b3,
                                             float* __restrict__ dinv,
                                             unsigned short* __restrict__ adjb,
                                             unsigned short* __restrict__ WT,
                                             float* __restrict__ biasf) {
    if (blockIdx.x >= 16384) {                        // prep tail: W^T + bias
        const int e = (blockIdx.x - 16384) * 256 + threadIdx.x;
        if (e < 49152) {
            const int w = e >> 14, r = e & 16383;
            const int f = r & 127, k = r >> 7;
            const float* W = (w == 0) ? W1 : ((w == 1) ? W2 : W3);
            WT[w * 16384 + f * 128 + k] = f2bf(W[r]);
        } else if (e < 49536) {
            const int idx = e - 49152;
            const float* bp = (idx < 128) ? b1 : ((idx < 256) ? b2 : b3);
            biasf[idx] = bp[idx & 127];
        }
        return;
    }
    const int row = blockIdx.x;                       // 0..16383
    const size_t base = (size_t)row * 2048 + threadIdx.x * 8;
    const float4 a = *(const float4*)(adj + base);
    const float4 b = *(const float4*)(adj + base + 4);
    float s = a.x + a.y + a.z + a.w + b.x + b.y + b.z + b.w;
    union { uint4 u; unsigned short h[8]; } pk;
    pk.h[0] = f2bf(a.x); pk.h[1] = f2bf(a.y); pk.h[2] = f2bf(a.z); pk.h[3] = f2bf(a.w);
    pk.h[4] = f2bf(b.x); pk.h[5] = f2bf(b.y); pk.h[6] = f2bf(b.z); pk.h[7] = f2bf(b.w);
    *(uint4*)(adjb + base) = pk.u;
#pragma unroll
    for (int off = 32; off > 0; off >>= 1) s += __shfl_down(s, off);
    __shared__ float ws[4];
    if ((threadIdx.x & 63) == 0) ws[threadIdx.x >> 6] = s;
    __syncthreads();
    if (threadIdx.x == 0) {
        float t = ws[0] + ws[1] + ws[2] + ws[3];
        dinv[row] = (t > 0.f) ? rsqrtf(t) : 0.f;      // matches where(isinf,0)
    }
}

// ---- small GEMM: Hs = leakyrelu(A @ W + b) * dinv_j -> HsT (transposed) --
template <int AEXT>
__global__ __launch_bounds__(256) void k_gxw(const void* __restrict__ Asrc,
                                             const unsigned short* __restrict__ WTb,
                                             const float* __restrict__ biasf,
                                             const float* __restrict__ dinv,
                                             unsigned short* __restrict__ HsT) {
    constexpr int LDK = 136;                          // 128 + 8 pad
    __shared__ unsigned short Bs[128 * LDK];          // 34 KB

    const int tid  = threadIdx.x;
    const int wave = tid >> 6;
    const int lane = tid & 63;
    const int n_   = lane & 15;
    const int q    = lane >> 4;

    const int bb  = blockIdx.x;                       // 256 blocks
    const int b   = bb & 7;
    const int gr0 = b * 2048 + (bb >> 3) * 64;

#pragma unroll
    for (int it = 0; it < 8; ++it) {                  // stage full 128x128 WT
        int task = tid + it * 256;
        int f  = task >> 4;
        int cj = (task & 15) * 8;
        *(uint4*)(&Bs[f * LDK + cj]) = *(const uint4*)(WTb + f * 128 + cj);
    }
    __syncthreads();

    const int arow = gr0 + wave * 16 + n_;
    f32x4 acc[8];
#pragma unroll
    for (int i = 0; i < 8; ++i) acc[i] = (f32x4){0.f, 0.f, 0.f, 0.f};

#pragma unroll
    for (int s = 0; s < 4; ++s) {                     // K = 4 x 32
        bf16x8 a;
        if (AEXT) {
            const float* p = (const float*)Asrc + (size_t)arow * 128 + s * 32 + q * 8;
            float4 u = ((const float4*)p)[0], w = ((const float4*)p)[1];
            union { bf16x8 v; unsigned short h[8]; } r;
            r.h[0] = f2bf(u.x); r.h[1] = f2bf(u.y); r.h[2] = f2bf(u.z); r.h[3] = f2bf(u.w);
            r.h[4] = f2bf(w.x); r.h[5] = f2bf(w.y); r.h[6] = f2bf(w.z); r.h[7] = f2bf(w.w);
            a = r.v;
        } else {
            a = *(const bf16x8*)((const unsigned short*)Asrc + (size_t)arow * 128 + s * 32 + q * 8);
        }
#pragma unroll
        for (int nt = 0; nt < 8; ++nt) {
            bf16x8 bv = *(const bf16x8*)(&Bs[(nt * 16 + n_) * LDK + s * 32 + q * 8]);
            acc[nt] = __builtin_amdgcn_mfma_f32_16x16x32_bf16(a, bv, acc[nt], 0, 0, 0);
        }
    }

    // C/D: col = lane&15, row = quad*4 + reg
    const int rbase = gr0 + wave * 16 + q * 4;
    float dsc[4];
#pragma unroll
    for (int r = 0; r < 4; ++r) dsc[r] = dinv[rbase + r];
    const int jbase = (gr0 & 2047) + wave * 16 + q * 4;
    unsigned short* Hb = HsT + (size_t)b * (128 * 2048);
#pragma unroll
    for (int nt = 0; nt < 8; ++nt) {
        const int f = nt * 16 + n_;
        const float bf = biasf[f];
        unsigned short pk[4];
#pragma unroll
        for (int r = 0; r < 4; ++r) {
            float v = acc[nt][r] + bf;
            v = (v > 0.f) ? v : 0.01f * v;            // LeakyReLU(0.01)
            pk[r] = f2bf(v * dsc[r]);                 // * dinv_j
        }
        uint2 u;
        u.x = (unsigned int)pk[0] | ((unsigned int)pk[1] << 16);
        u.y = (unsigned int)pk[2] | ((unsigned int)pk[3] << 16);
        *(uint2*)(Hb + (size_t)f * 2048 + jbase) = u; // HsT[b][f][j]
    }
}

// ---- big GEMM (K-split 2): Xp[ks] = adjb[:, k0:k0+1024] @ HsT^T ----------
// Grid 512: b=bb&7 (batch->XCD), ks=(bb>>3)&1, rowblk=bb>>4 (0..31).
// Block 64 rows x 128 cols x K=1024. Wave 32x64 (2 A-frag x 4 B-frag).
// Double-buffered LDS + register prefetch. fp32 partial store (no scaling).
__global__ __launch_bounds__(256) void k_gah(const unsigned short* __restrict__ adjb,
                                             const unsigned short* __restrict__ HsT,
                                             float* __restrict__ Xp) {
    constexpr int LDB = 72;                           // 64 + 8 pad
    constexpr int TILE = 128 * LDB;
    constexpr int NT = 16;                            // 16 k-tiles of 64
    __shared__ unsigned short Bs[2 * TILE];           // 36 KB

    const int tid  = threadIdx.x;
    const int wave = tid >> 6;
    const int lane = tid & 63;
    const int n_   = lane & 15;
    const int q    = lane >> 4;
    const int wm   = wave >> 1;
    const int wn   = wave & 1;

    const int bb  = blockIdx.x;                       // 512 blocks
    const int b   = bb & 7;                           // batch -> XCD affinity
    const int ks  = (bb >> 3) & 1;                    // K half
    const int gr0 = b * 2048 + (bb >> 4) * 64;        // block row base
    const int k0  = ks * 1024;

    const unsigned short* Bb = HsT + (size_t)b * (128 * 2048);
    const int fbase = tid >> 3;                       // 0..31 (+ it*32)
    const int cjc   = (tid & 7) * 8;
    const unsigned short* Bg[4];
    unsigned short* Bw[4];
#pragma unroll
    for (int it = 0; it < 4; ++it) {
        Bg[it] = Bb + (size_t)(fbase + it * 32) * 2048 + k0 + cjc;
        Bw[it] = &Bs[(fbase + it * 32) * LDB + cjc];
    }
    const unsigned short* A0 = adjb + (size_t)(gr0 + wm * 32 + n_) * 2048 + k0 + q * 8;
    const unsigned short* A1 = A0 + 16 * 2048;

    f32x4 acc[2][4];
#pragma unroll
    for (int i = 0; i < 2; ++i)
#pragma unroll
        for (int j = 0; j < 4; ++j) acc[i][j] = (f32x4){0.f, 0.f, 0.f, 0.f};

    // prologue: tile 0
    uint4 st[4];
#pragma unroll
    for (int it = 0; it < 4; ++it) st[it] = *(const uint4*)(Bg[it]);
    bf16x8 aA[2][4];
#pragma unroll
    for (int s = 0; s < 2; ++s) {
        aA[0][s * 2 + 0] = *(const bf16x8*)(A0 + s * 32);
        aA[0][s * 2 + 1] = *(const bf16x8*)(A1 + s * 32);
    }
#pragma unroll
    for (int it = 0; it < 4; ++it) *(uint4*)(Bw[it]) = st[it];
    __syncthreads();

    const int wn64 = wn * 64;
    auto step = [&](int kc2, int cur) {
        const int kn = (kc2 + 1) * 64;
        if (kc2 != NT - 1) {                          // prefetch tile kc2+1
#pragma unroll
            for (int it = 0; it < 4; ++it) st[it] = *(const uint4*)(Bg[it] + kn);
#pragma unroll
            for (int s = 0; s < 2; ++s) {
                aA[cur ^ 1][s * 2 + 0] = *(const bf16x8*)(A0 + kn + s * 32);
                aA[cur ^ 1][s * 2 + 1] = *(const bf16x8*)(A1 + kn + s * 32);
            }
        }
        const unsigned short* bs = &Bs[cur * TILE];
#pragma unroll
        for (int s = 0; s < 2; ++s) {
            bf16x8 a0 = aA[cur][s * 2 + 0];
            bf16x8 a1 = aA[cur][s * 2 + 1];
#pragma unroll
            for (int nt = 0; nt < 4; ++nt) {
                bf16x8 bv = *(const bf16x8*)(&bs[(wn64 + nt * 16 + n_) * LDB + s * 32 + q * 8]);
                acc[0][nt] = __builtin_amdgcn_mfma_f32_16x16x32_bf16(a0, bv, acc[0][nt], 0, 0, 0);
                acc[1][nt] = __builtin_amdgcn_mfma_f32_16x16x32_bf16(a1, bv, acc[1][nt], 0, 0, 0);
            }
        }
        if (kc2 != NT - 1) {
            unsigned short* bw = &Bs[(cur ^ 1) * TILE];
#pragma unroll
            for (int it = 0; it < 4; ++it) *(uint4*)(bw + (Bw[it] - Bs)) = st[it];
        }
        __syncthreads();
    };
    for (int kc2 = 0; kc2 < NT; kc2 += 2) { step(kc2, 0); step(kc2 + 1, 1); }

    // fp32 partial store. C/D: col = lane&15, row = quad*4 + reg
    float* Pp = Xp + (size_t)ks * PLANE;
    const int rb0 = gr0 + wm * 32 + q * 4;
#pragma unroll
    for (int mi = 0; mi < 2; ++mi) {
#pragma unroll
        for (int nt = 0; nt < 4; ++nt) {
            const int f = wn64 + nt * 16 + n_;
#pragma unroll
            for (int r = 0; r < 4; ++r)
                Pp[(size_t)(rb0 + mi * 16 + r) * 128 + f] = acc[mi][nt][r];
        }
    }
}

// ---- combine K-split partials: out = (p0+p1)*dinv_i [+resid] -------------
template <int RES, int OUT32>
__global__ __launch_bounds__(256) void k_fin(const float* __restrict__ Xp,
                                             const float* __restrict__ dinv,
                                             const unsigned short* __restrict__ resid,
                                             void* __restrict__ outp) {
    const int i = (blockIdx.x * 256 + threadIdx.x) * 4;   // 4 consecutive f
    const float d = dinv[i >> 7];
    float4 a = *(const float4*)(Xp + i);
    float4 b = *(const float4*)(Xp + PLANE + i);
    float v0 = (a.x + b.x) * d, v1 = (a.y + b.y) * d;
    float v2 = (a.z + b.z) * d, v3 = (a.w + b.w) * d;
    if (RES) {
        uint2 r = *(const uint2*)(resid + i);
        v0 += bf2f((unsigned short)(r.x & 0xFFFF));
        v1 += bf2f((unsigned short)(r.x >> 16));
        v2 += bf2f((unsigned short)(r.y & 0xFFFF));
        v3 += bf2f((unsigned short)(r.y >> 16));
    }
    if (OUT32) {
        float4 o; o.x = v0; o.y = v1; o.z = v2; o.w = v3;
        *(float4*)((float*)outp + i) = o;
    } else {
        uint2 u;
        u.x = (unsigned int)f2bf(v0) | ((unsigned int)f2bf(v1) << 16);
        u.y = (unsigned int)f2bf(v2) | ((unsigned int)f2bf(v3) << 16);
        *(uint2*)((unsigned short*)outp + i) = u;
    }
}

extern "C" void kernel_launch(void* const* d_in, const int* in_sizes, int n_in,
                              void* d_out, int out_size, void* d_ws, size_t ws_size,
                              hipStream_t stream) {
    const float* X   = (const float*)d_in[0];
    const float* adj = (const float*)d_in[1];
    const float* W1  = (const float*)d_in[2];
    const float* b1  = (const float*)d_in[3];
    const float* W2  = (const float*)d_in[4];
    const float* b2  = (const float*)d_in[5];
    const float* W3  = (const float*)d_in[6];
    const float* b3  = (const float*)d_in[7];

    // ws: dinv @0 | biasf @64K | WT @128K | HsT @256K (4M) | Xa @+4M (4M) |
    //     X2 @+8M (4M) | Xp @+12M (16M) | adjb @+28M (67M)  -> ~96 MB
    char* ws = (char*)d_ws;
    float*          dinv  = (float*)ws;
    float*          biasf = (float*)(ws + (64 << 10));
    unsigned short* WT    = (unsigned short*)(ws + (128 << 10));
    unsigned short* HsT   = (unsigned short*)(ws + (256 << 10));
    unsigned short* Xa    = (unsigned short*)(ws + (256 << 10) + (4 << 20));
    unsigned short* X2    = (unsigned short*)(ws + (256 << 10) + (8 << 20));
    float*          Xp    = (float*)(ws + (256 << 10) + (12 << 20));
    unsigned short* adjb  = (unsigned short*)(ws + (256 << 10) + (28 << 20));

    k_pre<<<16578, 256, 0, stream>>>(adj, W1, W2, W3, b1, b2, b3, dinv, adjb, WT, biasf);

    // layer 1
    k_gxw<1><<<256, 256, 0, stream>>>(X, WT, biasf, dinv, HsT);
    k_gah<<<512, 256, 0, stream>>>(adjb, HsT, Xp);
    k_fin<0, 0><<<2048, 256, 0, stream>>>(Xp, dinv, nullptr, Xa);
    // layer 2 (residual = Xa)
    k_gxw<0><<<256, 256, 0, stream>>>(Xa, WT + 16384, biasf + 128, dinv, HsT);
    k_gah<<<512, 256, 0, stream>>>(adjb, HsT, Xp);
    k_fin<1, 0><<<2048, 256, 0, stream>>>(Xp, dinv, Xa, X2);
    // layer 3 -> fp32 out
    k_gxw<0><<<256, 256, 0, stream>>>(X2, WT + 32768, biasf + 256, dinv, HsT);
    k_gah<<<512, 256, 0, stream>>>(adjb, HsT, Xp);
    k_fin<0, 1><<<2048, 256, 0, stream>>>(Xp, dinv, nullptr, (float*)d_out);
}

// Round 6
// 372.148 us; speedup vs baseline: 1.0094x; 1.0094x over previous
//
#include <hip/hip_runtime.h>

// Residual GCN, MI355X. B=8, N=2048, D=128. External dtype fp32 (verified R3).
// out = dinv_i * (A @ (dinv_j * leakyrelu(X@W + b))) [+ X]
// Internal bf16 + MFMA 16x16x32 bf16, fp32 accumulate.
// R6: 5 dispatches. Big GEMM fuses the NEXT layer's X@W+bias+lrelu+dinv_j
// (mini-GEMM vs L1-resident WT) into its epilogue; X2 never hits HBM.

typedef short bf16x8 __attribute__((ext_vector_type(8)));
typedef float f32x4 __attribute__((ext_vector_type(4)));

static __device__ __forceinline__ float bf2f(unsigned short h) {
    union { unsigned int u; float f; } v; v.u = ((unsigned int)h) << 16; return v.f;
}
static __device__ __forceinline__ unsigned short f2bf(float x) {  // RNE
    union { float f; unsigned int u; } v; v.f = x;
    return (unsigned short)((v.u + 0x7FFFu + ((v.u >> 16) & 1u)) >> 16);
}

// ---- fused: adj rowsum -> dinv, adj fp32 -> bf16, W transpose, bias ------
__global__ __launch_bounds__(256) void k_pre(const float* __restrict__ adj,
                                             const float* __restrict__ W1,
                                             const float* __restrict__ W2,
                                             const float* __restrict__ W3,
                                             const float* __restrict__ b1,
                                             const float* __restrict__ b2,
                                             const float* __restrict__ b3,
                                             float* __restrict__ dinv,
                                             unsigned short* __restrict__ adjb,
                                             unsigned short* __restrict__ WT,
                                             float* __restrict__ biasf) {
    if (blockIdx.x >= 16384) {                        // prep tail: W^T + bias
        const int e = (blockIdx.x - 16384) * 256 + threadIdx.x;
        if (e < 49152) {
            const int w = e >> 14, r = e & 16383;
            const int f = r & 127, k = r >> 7;
            const float* W = (w == 0) ? W1 : ((w == 1) ? W2 : W3);
            WT[w * 16384 + f * 128 + k] = f2bf(W[r]);
        } else if (e < 49536) {
            const int idx = e - 49152;
            const float* bp = (idx < 128) ? b1 : ((idx < 256) ? b2 : b3);
            biasf[idx] = bp[idx & 127];
        }
        return;
    }
    const int row = blockIdx.x;                       // 0..16383
    const size_t base = (size_t)row * 2048 + threadIdx.x * 8;
    const float4 a = *(const float4*)(adj + base);
    const float4 b = *(const float4*)(adj + base + 4);
    float s = a.x + a.y + a.z + a.w + b.x + b.y + b.z + b.w;
    union { uint4 u; unsigned short h[8]; } pk;
    pk.h[0] = f2bf(a.x); pk.h[1] = f2bf(a.y); pk.h[2] = f2bf(a.z); pk.h[3] = f2bf(a.w);
    pk.h[4] = f2bf(b.x); pk.h[5] = f2bf(b.y); pk.h[6] = f2bf(b.z); pk.h[7] = f2bf(b.w);
    *(uint4*)(adjb + base) = pk.u;
#pragma unroll
    for (int off = 32; off > 0; off >>= 1) s += __shfl_down(s, off);
    __shared__ float ws[4];
    if ((threadIdx.x & 63) == 0) ws[threadIdx.x >> 6] = s;
    __syncthreads();
    if (threadIdx.x == 0) {
        float t = ws[0] + ws[1] + ws[2] + ws[3];
        dinv[row] = (t > 0.f) ? rsqrtf(t) : 0.f;      // matches where(isinf,0)
    }
}

// ---- small GEMM (layer 1 only): HsT = (lrelu(X@W1+b1)*dinv_j)^T ----------
__global__ __launch_bounds__(256) void k_gxw(const float* __restrict__ Asrc,
                                             const unsigned short* __restrict__ WTb,
                                             const float* __restrict__ biasf,
                                             const float* __restrict__ dinv,
                                             unsigned short* __restrict__ HsT) {
    constexpr int LDK = 136;                          // 128 + 8 pad
    __shared__ unsigned short Bs[128 * LDK];          // 34 KB

    const int tid  = threadIdx.x;
    const int wave = tid >> 6;
    const int lane = tid & 63;
    const int n_   = lane & 15;
    const int q    = lane >> 4;

    const int bb  = blockIdx.x;                       // 256 blocks
    const int b   = bb & 7;
    const int gr0 = b * 2048 + (bb >> 3) * 64;

#pragma unroll
    for (int it = 0; it < 8; ++it) {                  // stage full 128x128 WT
        int task = tid + it * 256;
        int f  = task >> 4;
        int cj = (task & 15) * 8;
        *(uint4*)(&Bs[f * LDK + cj]) = *(const uint4*)(WTb + f * 128 + cj);
    }
    __syncthreads();

    const int arow = gr0 + wave * 16 + n_;
    f32x4 acc[8];
#pragma unroll
    for (int i = 0; i < 8; ++i) acc[i] = (f32x4){0.f, 0.f, 0.f, 0.f};

#pragma unroll
    for (int s = 0; s < 4; ++s) {                     // K = 4 x 32
        const float* p = Asrc + (size_t)arow * 128 + s * 32 + q * 8;
        float4 u = ((const float4*)p)[0], w = ((const float4*)p)[1];
        union { bf16x8 v; unsigned short h[8]; } r;
        r.h[0] = f2bf(u.x); r.h[1] = f2bf(u.y); r.h[2] = f2bf(u.z); r.h[3] = f2bf(u.w);
        r.h[4] = f2bf(w.x); r.h[5] = f2bf(w.y); r.h[6] = f2bf(w.z); r.h[7] = f2bf(w.w);
        bf16x8 a = r.v;
#pragma unroll
        for (int nt = 0; nt < 8; ++nt) {
            bf16x8 bv = *(const bf16x8*)(&Bs[(nt * 16 + n_) * LDK + s * 32 + q * 8]);
            acc[nt] = __builtin_amdgcn_mfma_f32_16x16x32_bf16(a, bv, acc[nt], 0, 0, 0);
        }
    }

    // C/D: col = lane&15, row = quad*4 + reg
    const int rbase = gr0 + wave * 16 + q * 4;
    float dsc[4];
#pragma unroll
    for (int r = 0; r < 4; ++r) dsc[r] = dinv[rbase + r];
    const int jbase = (gr0 & 2047) + wave * 16 + q * 4;
    unsigned short* Hb = HsT + (size_t)b * (128 * 2048);
#pragma unroll
    for (int nt = 0; nt < 8; ++nt) {
        const int f = nt * 16 + n_;
        const float bf = biasf[f];
        unsigned short pk[4];
#pragma unroll
        for (int r = 0; r < 4; ++r) {
            float v = acc[nt][r] + bf;
            v = (v > 0.f) ? v : 0.01f * v;            // LeakyReLU(0.01)
            pk[r] = f2bf(v * dsc[r]);                 // * dinv_j
        }
        uint2 u;
        u.x = (unsigned int)pk[0] | ((unsigned int)pk[1] << 16);
        u.y = (unsigned int)pk[2] | ((unsigned int)pk[3] << 16);
        *(uint2*)(Hb + (size_t)f * 2048 + jbase) = u; // HsT[b][f][j]
    }
}

// ---- fused big GEMM + next-layer mini-GEMM -------------------------------
// Xn = adjb @ HsTin^T * dinv_i [+ resid]     (64x128 per block, K=2048)
// MODE 0: store Xn (bf16, ->Xa) AND HsTout = (lrelu(Xn@Wn+bn)*dinv_j)^T
// MODE 1: resid=Xa, no Xn store; HsTout from residual-added Xn
// MODE 2: store Xn as fp32 -> fout (final layer)
template <int MODE>
__global__ __launch_bounds__(256) void k_fuse(const unsigned short* __restrict__ adjb,
                                              const unsigned short* __restrict__ HsTin,
                                              const float* __restrict__ dinv,
                                              const float* __restrict__ biasn,
                                              const unsigned short* __restrict__ WTn,
                                              const unsigned short* __restrict__ resid,
                                              unsigned short* __restrict__ XaOut,
                                              unsigned short* __restrict__ HsTout,
                                              float* __restrict__ fout) {
    constexpr int LDB = 72;                           // 64 + 8 pad
    constexpr int TILE = 128 * LDB;
    constexpr int NT = 32;                            // K = 32 x 64
    __shared__ unsigned short Bs[2 * TILE];           // 36 KB

    const int tid  = threadIdx.x;
    const int wave = tid >> 6;
    const int lane = tid & 63;
    const int n_   = lane & 15;
    const int q    = lane >> 4;
    const int wm   = wave >> 1;
    const int wn   = wave & 1;

    const int bb  = blockIdx.x;                       // 256 blocks
    const int b   = bb & 7;                           // batch -> XCD affinity
    const int gr0 = b * 2048 + (bb >> 3) * 64;

    const unsigned short* Bb = HsTin + (size_t)b * (128 * 2048);
    const int fbase = tid >> 3;
    const int cjc   = (tid & 7) * 8;
    const unsigned short* Bg[4];
    unsigned short* Bw[4];
#pragma unroll
    for (int it = 0; it < 4; ++it) {
        Bg[it] = Bb + (size_t)(fbase + it * 32) * 2048 + cjc;
        Bw[it] = &Bs[(fbase + it * 32) * LDB + cjc];
    }
    const unsigned short* A0 = adjb + (size_t)(gr0 + wm * 32 + n_) * 2048 + q * 8;
    const unsigned short* A1 = A0 + 16 * 2048;

    f32x4 acc[2][4];
#pragma unroll
    for (int i = 0; i < 2; ++i)
#pragma unroll
        for (int j = 0; j < 4; ++j) acc[i][j] = (f32x4){0.f, 0.f, 0.f, 0.f};

    // prologue: tile 0
    uint4 st[4];
#pragma unroll
    for (int it = 0; it < 4; ++it) st[it] = *(const uint4*)(Bg[it]);
    bf16x8 aA[2][4];
#pragma unroll
    for (int s = 0; s < 2; ++s) {
        aA[0][s * 2 + 0] = *(const bf16x8*)(A0 + s * 32);
        aA[0][s * 2 + 1] = *(const bf16x8*)(A1 + s * 32);
    }
#pragma unroll
    for (int it = 0; it < 4; ++it) *(uint4*)(Bw[it]) = st[it];
    __syncthreads();

    const int wn64 = wn * 64;
    auto step = [&](int kc2, int cur) {
        const int kn = (kc2 + 1) * 64;
        if (kc2 != NT - 1) {                          // prefetch tile kc2+1
#pragma unroll
            for (int it = 0; it < 4; ++it) st[it] = *(const uint4*)(Bg[it] + kn);
#pragma unroll
            for (int s = 0; s < 2; ++s) {
                aA[cur ^ 1][s * 2 + 0] = *(const bf16x8*)(A0 + kn + s * 32);
                aA[cur ^ 1][s * 2 + 1] = *(const bf16x8*)(A1 + kn + s * 32);
            }
        }
        const unsigned short* bs = &Bs[cur * TILE];
#pragma unroll
        for (int s = 0; s < 2; ++s) {
            bf16x8 a0 = aA[cur][s * 2 + 0];
            bf16x8 a1 = aA[cur][s * 2 + 1];
#pragma unroll
            for (int nt = 0; nt < 4; ++nt) {
                bf16x8 bv = *(const bf16x8*)(&bs[(wn64 + nt * 16 + n_) * LDB + s * 32 + q * 8]);
                acc[0][nt] = __builtin_amdgcn_mfma_f32_16x16x32_bf16(a0, bv, acc[0][nt], 0, 0, 0);
                acc[1][nt] = __builtin_amdgcn_mfma_f32_16x16x32_bf16(a1, bv, acc[1][nt], 0, 0, 0);
            }
        }
        if (kc2 != NT - 1) {
            unsigned short* bw = &Bs[(cur ^ 1) * TILE];
#pragma unroll
            for (int it = 0; it < 4; ++it) *(uint4*)(bw + (Bw[it] - Bs)) = st[it];
        }
        __syncthreads();
    };
    for (int kc2 = 0; kc2 < NT; kc2 += 2) { step(kc2, 0); step(kc2 + 1, 1); }

    // ---- epilogue 1: Xn = acc*dinv_i [+resid]; optional global store -----
    const int rb0 = gr0 + wm * 32 + q * 4;
    float dsc[2][4];
#pragma unroll
    for (int mi = 0; mi < 2; ++mi)
#pragma unroll
        for (int r = 0; r < 4; ++r) dsc[mi][r] = dinv[rb0 + mi * 16 + r];

    unsigned short ob[2][4][4];                       // Xn bf16 [mi][nt][r]
#pragma unroll
    for (int mi = 0; mi < 2; ++mi) {
#pragma unroll
        for (int nt = 0; nt < 4; ++nt) {
            const int f = wn64 + nt * 16 + n_;
#pragma unroll
            for (int r = 0; r < 4; ++r) {
                const int gr = rb0 + mi * 16 + r;
                float v = acc[mi][nt][r] * dsc[mi][r];        // * dinv_i
                if (MODE == 1) v += bf2f(resid[(size_t)gr * 128 + f]);
                if (MODE == 2) { fout[(size_t)gr * 128 + f] = v; continue; }
                ob[mi][nt][r] = f2bf(v);
                if (MODE == 0) XaOut[(size_t)gr * 128 + f] = ob[mi][nt][r];
            }
        }
    }
    if (MODE == 2) return;

    // ---- epilogue 2: mini-GEMM Hs_next = lrelu(Xn@Wn+bn)*dinv_j -> HsTout -
    // Transpose Xn tile into LDS: Ot[f][row_local], LDB=72 pad.
    unsigned short* Ot = (unsigned short*)Bs;         // 128 x 72 = 18 KB
    __syncthreads();                                  // Bs dead (post K-loop)
#pragma unroll
    for (int mi = 0; mi < 2; ++mi) {
#pragma unroll
        for (int nt = 0; nt < 4; ++nt) {
            const int f = wn64 + nt * 16 + n_;
            const int rl = wm * 32 + mi * 16 + q * 4; // local row, mult of 4
            uint2 u;
            u.x = (unsigned int)ob[mi][nt][0] | ((unsigned int)ob[mi][nt][1] << 16);
            u.y = (unsigned int)ob[mi][nt][2] | ((unsigned int)ob[mi][nt][3] << 16);
            *(uint2*)(&Ot[f * LDB + rl]) = u;
        }
    }
    __syncthreads();

    f32x4 acc2[8];
#pragma unroll
    for (int i = 0; i < 8; ++i) acc2[i] = (f32x4){0.f, 0.f, 0.f, 0.f};
#pragma unroll
    for (int s = 0; s < 4; ++s) {                     // K = 4 x 32 (features)
        union { bf16x8 v; unsigned short h[8]; } a;   // A[m=n_][k]=Ot[k][row]
        const int rl = wave * 16 + n_;
#pragma unroll
        for (int j = 0; j < 8; ++j) a.h[j] = Ot[(s * 32 + q * 8 + j) * LDB + rl];
#pragma unroll
        for (int nt = 0; nt < 8; ++nt) {              // B from global WT (L1/L2-hot)
            bf16x8 bv = *(const bf16x8*)(WTn + (nt * 16 + n_) * 128 + s * 32 + q * 8);
            acc2[nt] = __builtin_amdgcn_mfma_f32_16x16x32_bf16(a.v, bv, acc2[nt], 0, 0, 0);
        }
    }

    const int rbase2 = gr0 + wave * 16 + q * 4;
    float ds2[4];
#pragma unroll
    for (int r = 0; r < 4; ++r) ds2[r] = dinv[rbase2 + r];
    const int jbase = (gr0 & 2047) + wave * 16 + q * 4;
    unsigned short* Hb = HsTout + (size_t)b * (128 * 2048);
#pragma unroll
    for (int nt = 0; nt < 8; ++nt) {
        const int f = nt * 16 + n_;
        const float bf = biasn[f];
        unsigned short pk[4];
#pragma unroll
        for (int r = 0; r < 4; ++r) {
            float v = acc2[nt][r] + bf;
            v = (v > 0.f) ? v : 0.01f * v;            // LeakyReLU(0.01)
            pk[r] = f2bf(v * ds2[r]);                 // * dinv_j
        }
        uint2 u;
        u.x = (unsigned int)pk[0] | ((unsigned int)pk[1] << 16);
        u.y = (unsigned int)pk[2] | ((unsigned int)pk[3] << 16);
        *(uint2*)(Hb + (size_t)f * 2048 + jbase) = u; // HsT[b][f][j]
    }
}

extern "C" void kernel_launch(void* const* d_in, const int* in_sizes, int n_in,
                              void* d_out, int out_size, void* d_ws, size_t ws_size,
                              hipStream_t stream) {
    const float* X   = (const float*)d_in[0];
    const float* adj = (const float*)d_in[1];
    const float* W1  = (const float*)d_in[2];
    const float* b1  = (const float*)d_in[3];
    const float* W2  = (const float*)d_in[4];
    const float* b2  = (const float*)d_in[5];
    const float* W3  = (const float*)d_in[6];
    const float* b3  = (const float*)d_in[7];

    // ws: dinv @0 (64K) | biasf @64K | WT @128K (96K) | HsT1 @256K (4M) |
    //     HsT2 @+4M (4M) | Xa @+8M (4M) | adjb @+12M (67M)  -> ~80 MB
    char* ws = (char*)d_ws;
    float*          dinv  = (float*)ws;
    float*          biasf = (float*)(ws + (64 << 10));
    unsigned short* WT    = (unsigned short*)(ws + (128 << 10));
    unsigned short* HsT1  = (unsigned short*)(ws + (256 << 10));
    unsigned short* HsT2  = (unsigned short*)(ws + (256 << 10) + (4 << 20));
    unsigned short* Xa    = (unsigned short*)(ws + (256 << 10) + (8 << 20));
    unsigned short* adjb  = (unsigned short*)(ws + (256 << 10) + (12 << 20));

    k_pre<<<16578, 256, 0, stream>>>(adj, W1, W2, W3, b1, b2, b3, dinv, adjb, WT, biasf);
    // layer 1 X@W
    k_gxw<<<256, 256, 0, stream>>>(X, WT, biasf, dinv, HsT1);
    // layer 1 A@H  (+ fused layer-2 X@W)  -> Xa, HsT2
    k_fuse<0><<<256, 256, 0, stream>>>(adjb, HsT1, dinv, biasf + 128, WT + 16384,
                                       nullptr, Xa, HsT2, nullptr);
    // layer 2 A@H + residual (+ fused layer-3 X@W) -> HsT1 (X2 stays on-chip)
    k_fuse<1><<<256, 256, 0, stream>>>(adjb, HsT2, dinv, biasf + 256, WT + 32768,
                                       Xa, nullptr, HsT1, nullptr);
    // layer 3 A@H -> fp32 out
    k_fuse<2><<<256, 256, 0, stream>>>(adjb, HsT1, dinv, nullptr, nullptr,
                                       nullptr, nullptr, nullptr, (float*)d_out);
}

// Round 8
// 367.960 us; speedup vs baseline: 1.0209x; 1.0114x over previous
//
#include <hip/hip_runtime.h>

// Residual GCN, MI355X. B=8, N=2048, D=128 fixed. External dtype fp32.
// out = dinv_i * (A @ (dinv_j * leakyrelu(X@W + b))) [+ X]
// Internal pipeline bf16 + MFMA 16x16x32 bf16, fp32 accumulate.
// R8: revert to the best-measured configuration (R4 bench: 368.9 us).
// 7 dispatches: k_pre (rowsum+cvt+W^T), then per layer k_gxw + k_gah with
// fully fused epilogues. K-split (R5) and inter-layer fusion (R6) measured
// neutral; cooperative single-kernel (R7) failed to launch in this harness.

typedef short bf16x8 __attribute__((ext_vector_type(8)));
typedef float f32x4 __attribute__((ext_vector_type(4)));

static __device__ __forceinline__ float bf2f(unsigned short h) {
    union { unsigned int u; float f; } v; v.u = ((unsigned int)h) << 16; return v.f;
}
static __device__ __forceinline__ unsigned short f2bf(float x) {  // RNE
    union { float f; unsigned int u; } v; v.f = x;
    return (unsigned short)((v.u + 0x7FFFu + ((v.u >> 16) & 1u)) >> 16);
}

// ---- fused: adj rowsum -> dinv, adj fp32 -> bf16, W transpose, bias ------
__global__ __launch_bounds__(256) void k_pre(const float* __restrict__ adj,
                                             const float* __restrict__ W1,
                                             const float* __restrict__ W2,
                                             const float* __restrict__ W3,
                                             const float* __restrict__ b1,
                                             const float* __restrict__ b2,
                                             const float* __restrict__ b3,
                                             float* __restrict__ dinv,
                                             unsigned short* __restrict__ adjb,
                                             unsigned short* __restrict__ WT,
                                             float* __restrict__ biasf) {
    if (blockIdx.x >= 16384) {                        // prep tail: W^T + bias
        const int e = (blockIdx.x - 16384) * 256 + threadIdx.x;
        if (e < 49152) {
            const int w = e >> 14, r = e & 16383;
            const int f = r & 127, k = r >> 7;
            const float* W = (w == 0) ? W1 : ((w == 1) ? W2 : W3);
            WT[w * 16384 + f * 128 + k] = f2bf(W[r]);
        } else if (e < 49536) {
            const int idx = e - 49152;
            const float* bp = (idx < 128) ? b1 : ((idx < 256) ? b2 : b3);
            biasf[idx] = bp[idx & 127];
        }
        return;
    }
    const int row = blockIdx.x;                       // 0..16383
    const size_t base = (size_t)row * 2048 + threadIdx.x * 8;
    const float4 a = *(const float4*)(adj + base);
    const float4 b = *(const float4*)(adj + base + 4);
    float s = a.x + a.y + a.z + a.w + b.x + b.y + b.z + b.w;
    union { uint4 u; unsigned short h[8]; } pk;
    pk.h[0] = f2bf(a.x); pk.h[1] = f2bf(a.y); pk.h[2] = f2bf(a.z); pk.h[3] = f2bf(a.w);
    pk.h[4] = f2bf(b.x); pk.h[5] = f2bf(b.y); pk.h[6] = f2bf(b.z); pk.h[7] = f2bf(b.w);
    *(uint4*)(adjb + base) = pk.u;
#pragma unroll
    for (int off = 32; off > 0; off >>= 1) s += __shfl_down(s, off);
    __shared__ float ws[4];
    if ((threadIdx.x & 63) == 0) ws[threadIdx.x >> 6] = s;
    __syncthreads();
    if (threadIdx.x == 0) {
        float t = ws[0] + ws[1] + ws[2] + ws[3];
        dinv[row] = (t > 0.f) ? rsqrtf(t) : 0.f;      // matches where(isinf,0)
    }
}

// ---- small GEMM: Hs = leakyrelu(A @ W + b) * dinv_j -> HsT (transposed) --
template <int AEXT>
__global__ __launch_bounds__(256) void k_gxw(const void* __restrict__ Asrc,
                                             const unsigned short* __restrict__ WTb,
                                             const float* __restrict__ biasf,
                                             const float* __restrict__ dinv,
                                             unsigned short* __restrict__ HsT) {
    constexpr int LDK = 136;                          // 128 + 8 pad
    __shared__ unsigned short Bs[128 * LDK];          // 34 KB

    const int tid  = threadIdx.x;
    const int wave = tid >> 6;
    const int lane = tid & 63;
    const int n_   = lane & 15;
    const int q    = lane >> 4;

    const int bb  = blockIdx.x;                       // 256 blocks
    const int b   = bb & 7;
    const int gr0 = b * 2048 + (bb >> 3) * 64;

#pragma unroll
    for (int it = 0; it < 8; ++it) {                  // stage full 128x128 WT
        int task = tid + it * 256;
        int f  = task >> 4;
        int cj = (task & 15) * 8;
        *(uint4*)(&Bs[f * LDK + cj]) = *(const uint4*)(WTb + f * 128 + cj);
    }
    __syncthreads();

    const int arow = gr0 + wave * 16 + n_;
    f32x4 acc[8];
#pragma unroll
    for (int i = 0; i < 8; ++i) acc[i] = (f32x4){0.f, 0.f, 0.f, 0.f};

#pragma unroll
    for (int s = 0; s < 4; ++s) {                     // K = 4 x 32
        bf16x8 a;
        if (AEXT) {
            const float* p = (const float*)Asrc + (size_t)arow * 128 + s * 32 + q * 8;
            float4 u = ((const float4*)p)[0], w = ((const float4*)p)[1];
            union { bf16x8 v; unsigned short h[8]; } r;
            r.h[0] = f2bf(u.x); r.h[1] = f2bf(u.y); r.h[2] = f2bf(u.z); r.h[3] = f2bf(u.w);
            r.h[4] = f2bf(w.x); r.h[5] = f2bf(w.y); r.h[6] = f2bf(w.z); r.h[7] = f2bf(w.w);
            a = r.v;
        } else {
            a = *(const bf16x8*)((const unsigned short*)Asrc + (size_t)arow * 128 + s * 32 + q * 8);
        }
#pragma unroll
        for (int nt = 0; nt < 8; ++nt) {
            bf16x8 bv = *(const bf16x8*)(&Bs[(nt * 16 + n_) * LDK + s * 32 + q * 8]);
            acc[nt] = __builtin_amdgcn_mfma_f32_16x16x32_bf16(a, bv, acc[nt], 0, 0, 0);
        }
    }

    // C/D: col = lane&15, row = quad*4 + reg
    const int rbase = gr0 + wave * 16 + q * 4;
    float dsc[4];
#pragma unroll
    for (int r = 0; r < 4; ++r) dsc[r] = dinv[rbase + r];
    const int jbase = (gr0 & 2047) + wave * 16 + q * 4;
    unsigned short* Hb = HsT + (size_t)b * (128 * 2048);
#pragma unroll
    for (int nt = 0; nt < 8; ++nt) {
        const int f = nt * 16 + n_;
        const float bf = biasf[f];
        unsigned short pk[4];
#pragma unroll
        for (int r = 0; r < 4; ++r) {
            float v = acc[nt][r] + bf;
            v = (v > 0.f) ? v : 0.01f * v;            // LeakyReLU(0.01)
            pk[r] = f2bf(v * dsc[r]);                 // * dinv_j
        }
        uint2 u;
        u.x = (unsigned int)pk[0] | ((unsigned int)pk[1] << 16);
        u.y = (unsigned int)pk[2] | ((unsigned int)pk[3] << 16);
        *(uint2*)(Hb + (size_t)f * 2048 + jbase) = u; // HsT[b][f][j]
    }
}

// ---- big GEMM: out = (adjb @ HsT^T) * dinv_i [+resid] --------------------
// adjb: 16384 x 2048 bf16. HsT: per-batch 128 x 2048 bf16.
// Block: 64 rows x 128 cols; wave: 32x64 (2 A-frag x 4 B-frag, 2:1 reuse).
// Double-buffered LDS, register prefetch of A and staging tile.
// MODE 1: store (*dinv_i); MODE 2: +resid. OUT32: fp32 store else bf16.
template <int MODE, int OUT32>
__global__ __launch_bounds__(256) void k_gah(const unsigned short* __restrict__ adjb,
                                             const unsigned short* __restrict__ HsT,
                                             const float* __restrict__ dinv,
                                             const unsigned short* __restrict__ resid,
                                             void* __restrict__ outp) {
    constexpr int LDB = 72;                           // 64 + 8 pad (2-way = free)
    constexpr int TILE = 128 * LDB;
    __shared__ unsigned short Bs[2 * TILE];           // 36 KB

    const int tid  = threadIdx.x;
    const int wave = tid >> 6;
    const int lane = tid & 63;
    const int n_   = lane & 15;
    const int q    = lane >> 4;
    const int wm   = wave >> 1;                       // 0..1 (row half)
    const int wn   = wave & 1;                        // 0..1 (col half)

    const int bb  = blockIdx.x;                       // 256 blocks
    const int b   = bb & 7;                           // batch -> XCD affinity
    const int gr0 = b * 2048 + (bb >> 3) * 64;

    const unsigned short* Bb = HsT + (size_t)b * (128 * 2048);
    const int fbase = tid >> 3;                       // 0..31 (+ it*32)
    const int cjc   = (tid & 7) * 8;                  // 0..56
    const unsigned short* Bg[4];
    unsigned short* Bw[4];
#pragma unroll
    for (int it = 0; it < 4; ++it) {
        Bg[it] = Bb + (size_t)(fbase + it * 32) * 2048 + cjc;
        Bw[it] = &Bs[(fbase + it * 32) * LDB + cjc];
    }
    const unsigned short* A0 = adjb + (size_t)(gr0 + wm * 32 + n_) * 2048 + q * 8;
    const unsigned short* A1 = A0 + 16 * 2048;

    f32x4 acc[2][4];
#pragma unroll
    for (int i = 0; i < 2; ++i)
#pragma unroll
        for (int j = 0; j < 4; ++j) acc[i][j] = (f32x4){0.f, 0.f, 0.f, 0.f};

    // prologue: tile 0
    uint4 st[4];
#pragma unroll
    for (int it = 0; it < 4; ++it) st[it] = *(const uint4*)(Bg[it]);
    bf16x8 aA[2][4];                                  // [parity][2 rows x 2 s]
#pragma unroll
    for (int s = 0; s < 2; ++s) {
        aA[0][s * 2 + 0] = *(const bf16x8*)(A0 + s * 32);
        aA[0][s * 2 + 1] = *(const bf16x8*)(A1 + s * 32);
    }
#pragma unroll
    for (int it = 0; it < 4; ++it) *(uint4*)(Bw[it]) = st[it];
    __syncthreads();

    const int wn64 = wn * 64;
    auto step = [&](int kc2, int cur) {
        const int kn = (kc2 + 1) * 64;
        if (kc2 != 31) {                              // prefetch tile kc2+1
#pragma unroll
            for (int it = 0; it < 4; ++it) st[it] = *(const uint4*)(Bg[it] + kn);
#pragma unroll
            for (int s = 0; s < 2; ++s) {
                aA[cur ^ 1][s * 2 + 0] = *(const bf16x8*)(A0 + kn + s * 32);
                aA[cur ^ 1][s * 2 + 1] = *(const bf16x8*)(A1 + kn + s * 32);
            }
        }
        const unsigned short* bs = &Bs[cur * TILE];
#pragma unroll
        for (int s = 0; s < 2; ++s) {
            bf16x8 a0 = aA[cur][s * 2 + 0];
            bf16x8 a1 = aA[cur][s * 2 + 1];
#pragma unroll
            for (int nt = 0; nt < 4; ++nt) {
                bf16x8 bv = *(const bf16x8*)(&bs[(wn64 + nt * 16 + n_) * LDB + s * 32 + q * 8]);
                acc[0][nt] = __builtin_amdgcn_mfma_f32_16x16x32_bf16(a0, bv, acc[0][nt], 0, 0, 0);
                acc[1][nt] = __builtin_amdgcn_mfma_f32_16x16x32_bf16(a1, bv, acc[1][nt], 0, 0, 0);
            }
        }
        if (kc2 != 31) {
            unsigned short* bw = &Bs[(cur ^ 1) * TILE];
#pragma unroll
            for (int it = 0; it < 4; ++it) *(uint4*)(bw + (Bw[it] - Bs)) = st[it];
        }
        __syncthreads();
    };
    for (int kc2 = 0; kc2 < 32; kc2 += 2) { step(kc2, 0); step(kc2 + 1, 1); }

    // epilogue. C/D: col = lane&15, row = quad*4 + reg
    const int rb0 = gr0 + wm * 32 + q * 4;
    float dsc[2][4];
#pragma unroll
    for (int mi = 0; mi < 2; ++mi)
#pragma unroll
        for (int r = 0; r < 4; ++r) dsc[mi][r] = dinv[rb0 + mi * 16 + r];
#pragma unroll
    for (int mi = 0; mi < 2; ++mi) {
#pragma unroll
        for (int nt = 0; nt < 4; ++nt) {
            const int f = wn64 + nt * 16 + n_;
#pragma unroll
            for (int r = 0; r < 4; ++r) {
                const int gr = rb0 + mi * 16 + r;
                float v = acc[mi][nt][r] * dsc[mi][r];    // * dinv_i
                if (MODE == 2) v += bf2f(resid[(size_t)gr * 128 + f]);
                if (OUT32) ((float*)outp)[(size_t)gr * 128 + f] = v;
                else ((unsigned short*)outp)[(size_t)gr * 128 + f] = f2bf(v);
            }
        }
    }
}

extern "C" void kernel_launch(void* const* d_in, const int* in_sizes, int n_in,
                              void* d_out, int out_size, void* d_ws, size_t ws_size,
                              hipStream_t stream) {
    const float* X   = (const float*)d_in[0];
    const float* adj = (const float*)d_in[1];
    const float* W1  = (const float*)d_in[2];
    const float* b1  = (const float*)d_in[3];
    const float* W2  = (const float*)d_in[4];
    const float* b2  = (const float*)d_in[5];
    const float* W3  = (const float*)d_in[6];
    const float* b3  = (const float*)d_in[7];

    // ws: dinv @0 (64K) | biasf @64K | WT @128K (96K) | HsT @256K (4M) |
    //     Xa @+4M (4M) | X2 @+8M (4M) | adjb @+12M (67M)  -> ~80 MB
    char* ws = (char*)d_ws;
    float*          dinv  = (float*)ws;
    float*          biasf = (float*)(ws + (64 << 10));
    unsigned short* WT    = (unsigned short*)(ws + (128 << 10));
    unsigned short* HsT   = (unsigned short*)(ws + (256 << 10));
    unsigned short* Xa    = (unsigned short*)(ws + (256 << 10) + (4 << 20));
    unsigned short* X2    = (unsigned short*)(ws + (256 << 10) + (8 << 20));
    unsigned short* adjb  = (unsigned short*)(ws + (256 << 10) + (12 << 20));

    k_pre<<<16578, 256, 0, stream>>>(adj, W1, W2, W3, b1, b2, b3, dinv, adjb, WT, biasf);

    // layer 1
    k_gxw<1><<<256, 256, 0, stream>>>(X, WT, biasf, dinv, HsT);
    k_gah<1, 0><<<256, 256, 0, stream>>>(adjb, HsT, dinv, nullptr, Xa);
    // layer 2 (residual = Xa)
    k_gxw<0><<<256, 256, 0, stream>>>(Xa, WT + 16384, biasf + 128, dinv, HsT);
    k_gah<2, 0><<<256, 256, 0, stream>>>(adjb, HsT, dinv, Xa, X2);
    // layer 3 -> fp32 out
    k_gxw<0><<<256, 256, 0, stream>>>(X2, WT + 32768, biasf + 256, dinv, HsT);
    k_gah<1, 1><<<256, 256, 0, stream>>>(adjb, HsT, dinv, nullptr, (float*)d_out);
}